// Round 2
// 514.037 us; speedup vs baseline: 1.0262x; 1.0262x over previous
//
#include <hip/hip_runtime.h>
#include <math.h>

#define BB 4
#define CCH 128
#define HH 384
#define WW 384

constexpr int TILE_X = 64;
constexpr int TILE_Y = 12;          // 768 blocks = exactly 3/CU (perfect balance)
constexpr int CC = 4;               // channels per staged chunk
constexpr int NCHUNK = CCH / CC;    // 32
constexpr int ROWS = TILE_Y + 2;    // 14 (rows y0 .. y0+13; fwd shifts need dy>=0)
constexpr int STR  = 72;            // floats per stage row; col l <-> gx = x0-4+l
constexpr int GR   = 18;            // float4 groups per row
constexpr int NVEC = CC * ROWS * GR;  // 1008 float4 per chunk
constexpr int NLD  = 4;             // 1008/256 -> uniform 4 loads/wave/chunk (tail clamped)
constexpr int BUFV = 4096;          // floats per buffer: 1024 float4 (16-slot pad for ragged tail)
constexpr int NSTR = 76;            // norm tile stride
#define EPSQ 1e-8f

// 12 forward shifts: (0,1),(0,2),(1,-2..2),(2,-2..2). Each unordered pair {p,q}
// visited once with weight sel(p)+sel(q) == reference's 24 directed shifts.
// Clamped staging addresses only affect don't-care values (pairs touching them
// have weight 0 because sel requires the 2-pixel interior margin).
//
// Pipeline: triple-buffered global_load_lds, prefetch depth 2, COUNTED vmcnt:
//   top of chunk k: {s_waitcnt vmcnt(4) lgkmcnt(0); s_barrier} as ONE asm block
//   (chunk k landed; chunk k+1's 4 loads stay in flight ACROSS the barrier),
//   then sched_barrier(0) so nothing (issue(k+2), ds_reads) hoists above it.
// Loads are wave-uniform (4/wave/chunk): the j=3 ragged tail is issued by all
// lanes with sources clamped to slot NVEC-1; HW writes base+lane*16 so the
// overflow lands in the 16-slot pad (slots 1008..1023), never read.
// Buffer-reuse safety: issue(k+2) overwrites the buffer read during chunk k-1;
// every wave passed the top-of-k barrier only after finishing its chunk k-1
// reads (lgkmcnt(0) is inside the same asm block as the barrier).

__global__ __launch_bounds__(256, 3)
void ctx_main(const float* __restrict__ er, const int* __restrict__ seg,
              const int* __restrict__ gt, float* __restrict__ Ssum,
              int* __restrict__ cntArr, int* __restrict__ bndArr)
{
    __shared__ __align__(16) float sbuf0[BUFV];   // 16384 B each
    __shared__ __align__(16) float sbuf1[BUFV];
    __shared__ __align__(16) float sbuf2[BUFV];
    __shared__ __align__(16) float normArr[ROWS * NSTR];  // 4256 B
    // total 53408 B -> 3 blocks/CU (3*53408 = 160224 <= 163840)

    const int tx  = threadIdx.x;            // 0..15 (x groups of 4 px)
    const int ty  = threadIdx.y;            // 0..15; ty<12 compute, ty>=12 stage-only wave
    const int tid = ty * 16 + tx;
    const int x0  = blockIdx.x * TILE_X;
    const int y0  = blockIdx.y * TILE_Y;
    const int b   = blockIdx.z;

    // ---- staging source offsets (within a CC-channel slab), computed once ----
    int srcOff[NLD];
    #pragma unroll
    for (int j = 0; j < NLD; ++j) {
        int id = tid + 256 * j; if (id > NVEC - 1) id = NVEC - 1;
        int c   = id / (ROWS * GR);
        int rem = id - c * (ROWS * GR);
        int r   = rem / GR;
        int g   = rem - r * GR;
        int gy  = y0 + r; if (gy > HH - 1) gy = HH - 1;
        int gx  = x0 - 4 + 4 * g;
        gx = min(max(gx, 0), WW - 4);
        srcOff[j] = (c * HH + gy) * WW + gx;
    }

    // ---- halo-norm pixel assignment (184 px):
    // rows 12,13 cols 2..69 (136) + rows 0..11 cols {2,3,68,69} (48).
    // Wave 3 (stage-only) takes h=0..63; tid 0..119 take h=64..183.
    int h = -1;
    if (tid >= 192)      h = tid - 192;
    else if (tid < 120)  h = 64 + tid;
    int hr = -1, hc = 0;
    if (h >= 0) {
        if (h < 136) { hr = TILE_Y + h / 68; hc = 2 + h % 68; }
        else {
            int t = h - 136;
            hr = t >> 2;
            int j = t & 3;
            hc = (j < 2) ? (2 + j) : (66 + j);   // 2,3,68,69
        }
    }

    float acc[12][4];
    #pragma unroll
    for (int s = 0; s < 12; ++s)
        #pragma unroll
        for (int i = 0; i < 4; ++i) acc[s][i] = 0.f;
    float nrm[4] = {0.f, 0.f, 0.f, 0.f};
    float haloN = 0.f;

    const float* erB = er + (size_t)b * CCH * HH * WW;

    auto issue = [&](int chunk, float* dst) {
        const float* erC = erB + (size_t)chunk * CC * HH * WW;
        #pragma unroll
        for (int j = 0; j < NLD; ++j) {
            __builtin_amdgcn_global_load_lds(
                (const __attribute__((address_space(1))) void*)(erC + srcOff[j]),
                (__attribute__((address_space(3))) void*)(dst + 4 * (tid + 256 * j)),
                16, 0, 0);
        }
    };

    // ---- prologue: chunks 0,1 in flight ----
    issue(0, sbuf0);
    issue(1, sbuf1);

    float* cA = sbuf0;   // chunk k   (current)
    float* cB = sbuf1;   // chunk k+1 (in flight)
    float* cC = sbuf2;   // chunk k+2 (issue target)

    for (int k = 0; k < NCHUNK; ++k) {
        float* cur = cA;
        // wait for chunk k's 4 loads (k+1's 4 stay in flight) + own ds_reads,
        // then barrier -- fused so nothing schedules between wait and barrier.
        if (k < NCHUNK - 1)
            asm volatile("s_waitcnt vmcnt(4) lgkmcnt(0)\n\ts_barrier" ::: "memory");
        else
            asm volatile("s_waitcnt vmcnt(0) lgkmcnt(0)\n\ts_barrier" ::: "memory");
        __builtin_amdgcn_sched_barrier(0);   // nothing hoists above the barrier
        if (k + 2 < NCHUNK) issue(k + 2, cC);

        // ---- accumulate dots (12 fwd shifts) + own norms; aligned b128 reads ----
        if (ty < TILE_Y) {
            #pragma unroll
            for (int c = 0; c < CC; ++c) {
                const float* rp = &cur[(c * ROWS + ty) * STR + 4 * tx];
                float L0[12], L1[12], L2[12];
                #pragma unroll
                for (int jj = 0; jj < 3; ++jj) {
                    *(float4*)&L0[4 * jj] = *(const float4*)(rp + 4 * jj);
                    *(float4*)&L1[4 * jj] = *(const float4*)(rp + STR + 4 * jj);
                    *(float4*)&L2[4 * jj] = *(const float4*)(rp + 2 * STR + 4 * jj);
                }
                #pragma unroll
                for (int i = 0; i < 4; ++i) {
                    float f = L0[4 + i];
                    nrm[i]    = fmaf(f, f,         nrm[i]);
                    acc[0][i] = fmaf(f, L0[5 + i], acc[0][i]);   // (0,+1)
                    acc[1][i] = fmaf(f, L0[6 + i], acc[1][i]);   // (0,+2)
                    #pragma unroll
                    for (int d = 0; d < 5; ++d) {                // dx = d-2
                        acc[2 + d][i] = fmaf(f, L1[2 + i + d], acc[2 + d][i]); // dy=1
                        acc[7 + d][i] = fmaf(f, L2[2 + i + d], acc[7 + d][i]); // dy=2
                    }
                }
            }
        }
        // ---- halo norm partials (from cur) ----
        if (hr >= 0) {
            #pragma unroll
            for (int c = 0; c < CC; ++c) {
                float v = cur[(c * ROWS + hr) * STR + hc];
                haloN = fmaf(v, v, haloN);
            }
        }

        // rotate buffers
        float* t = cA; cA = cB; cB = cC; cC = t;
    }

    // ---- build packed label/mask tile (reuse sbuf0) + norm tile ----
    // sbuf0 held chunk 30; its readers finished before the top-of-31 barrier.
    int* pkT = (int*)sbuf0;
    for (int it = tid; it < ROWS * STR; it += 256) {
        int r = it / STR, a = it - r * STR;
        int gy = y0 + r;
        int gx = x0 - 4 + a;
        int pk = 0;
        if (gy < HH && gx >= 0 && gx < WW) {
            int g   = gt[((size_t)b * HH + gy) * WW + gx];
            int gb  = (g == 255) ? 0 : g;
            int s0v = seg[(((size_t)b * 2 + 0) * HH + gy) * WW + gx];
            int s1v = seg[(((size_t)b * 2 + 1) * HH + gy) * WW + gx];
            int s1c = (s1v == 255) ? 0 : s1v;
            bool bnd   = (gb * s1c) > 0;
            bool inter = (gy >= 2 && gy <= HH - 3 && gx >= 2 && gx <= WW - 3);
            pk = (bnd ? 1 : 0) | ((bnd && inter) ? 2 : 0)
               | ((s0v & 255) << 8) | ((s1v & 255) << 16);
        }
        pkT[it] = pk;
    }
    if (ty < TILE_Y) {
        #pragma unroll
        for (int i = 0; i < 4; ++i)
            normArr[ty * NSTR + 4 * tx + 4 + i] = sqrtf(nrm[i]);
    }
    if (hr >= 0) normArr[hr * NSTR + hc] = sqrtf(haloN);
    __syncthreads();

    // ---- pair epilogue (12-wide windows; own px at indices 4..7) ----
    float Sth = 0.f; int cth = 0, bth = 0;
    if (ty < TILE_Y) {
        const float* nr = &normArr[ty * NSTR + 4 * tx];
        const int*   pr = &pkT[ty * STR + 4 * tx];
        float n0[12], n1[12], n2[12];
        int   p0[12], p1[12], p2[12];
        #pragma unroll
        for (int jj = 0; jj < 3; ++jj) {
            *(float4*)&n0[4 * jj] = *(const float4*)(nr + 4 * jj);
            *(float4*)&n1[4 * jj] = *(const float4*)(nr + NSTR + 4 * jj);
            *(float4*)&n2[4 * jj] = *(const float4*)(nr + 2 * NSTR + 4 * jj);
            *(int4*)&p0[4 * jj] = *(const int4*)(pr + 4 * jj);
            *(int4*)&p1[4 * jj] = *(const int4*)(pr + STR + 4 * jj);
            *(int4*)&p2[4 * jj] = *(const int4*)(pr + 2 * STR + 4 * jj);
        }

        #pragma unroll
        for (int i = 0; i < 4; ++i) {
            int pkP  = p0[4 + i];
            int selP = (pkP >> 1) & 1;
            cth += selP;
            bth += pkP & 1;
            float nP = fmaxf(n0[4 + i], EPSQ);
            auto doPair = [&](float dot, int pkQ, float nQv) {
                int w = selP + ((pkQ >> 1) & 1);
                if (w) {
                    float lab = (float)(((pkP >> 8) & 255) * ((pkQ >> 8) & 255)
                                      + ((pkP >> 16) & 255) * ((pkQ >> 16) & 255));
                    float cs = dot / (nP * fmaxf(nQv, EPSQ));
                    float d  = cs - lab;
                    Sth = fmaf((float)w * d, d, Sth);
                }
            };
            doPair(acc[0][i], p0[5 + i], n0[5 + i]);
            doPair(acc[1][i], p0[6 + i], n0[6 + i]);
            #pragma unroll
            for (int d2 = 0; d2 < 5; ++d2) {
                doPair(acc[2 + d2][i], p1[2 + i + d2], n1[2 + i + d2]);
                doPair(acc[7 + d2][i], p2[2 + i + d2], n2[2 + i + d2]);
            }
        }
    }

    // ---- reduce + atomics (one per wave; wave 3 contributes S=0) ----
    #pragma unroll
    for (int off = 32; off > 0; off >>= 1) {
        Sth += __shfl_down(Sth, off);
        cth += __shfl_down(cth, off);
        bth += __shfl_down(bth, off);
    }
    if ((tid & 63) == 0) {
        atomicAdd(&Ssum[b], Sth);
        atomicAdd(&cntArr[b], cth);
        atomicAdd(&bndArr[b], bth);
    }
}

__global__ void ctx_init(float* S, int* cnt, int* bnd) {
    int t = threadIdx.x;
    if (t < BB) { S[t] = 0.f; cnt[t] = 0; bnd[t] = 0; }
}

__global__ void ctx_finalize(const float* __restrict__ S, const int* __restrict__ cnt,
                             const int* __restrict__ bnd, float* __restrict__ out) {
    if (threadIdx.x == 0 && blockIdx.x == 0) {
        float tot = 0.f, nv = 0.f;
        for (int b = 0; b < BB; ++b) {
            if (bnd[b] >= 1) {
                float c = fmaxf((float)cnt[b], 1.f);
                tot += S[b] / (24.f * c);
                nv  += 1.f;
            }
        }
        tot = tot / fmaxf(nv, 1.f);
        if (isnan(tot)) tot = 0.f;
        out[0] = tot;
    }
}

extern "C" void kernel_launch(void* const* d_in, const int* in_sizes, int n_in,
                              void* d_out, int out_size, void* d_ws, size_t ws_size,
                              hipStream_t stream) {
    const float* er = (const float*)d_in[0];
    const int* seg  = (const int*)d_in[1];
    const int* gt   = (const int*)d_in[2];
    float* out = (float*)d_out;

    float* S   = (float*)d_ws;
    int*   cnt = (int*)d_ws + BB;
    int*   bnd = (int*)d_ws + 2 * BB;

    ctx_init<<<1, 64, 0, stream>>>(S, cnt, bnd);
    dim3 grid(WW / TILE_X, HH / TILE_Y, BB);
    dim3 block(16, 16);
    ctx_main<<<grid, block, 0, stream>>>(er, seg, gt, S, cnt, bnd);
    ctx_finalize<<<1, 64, 0, stream>>>(S, cnt, bnd, out);
}